// Round 1
// baseline (1083.668 us; speedup 1.0000x reference)
//
#include <hip/hip_runtime.h>

// PositionAttentionModule: B=2,C=64,C8=8,H=W=96,N=9216
// out[b,c,n] = sum_m V[b,m,c]*softmax_m(Q[b,n,:]·K[b,:,m])
// Round 1: fp32 VALU flash-style, constant-shift softmax (single pass).

#define BN 2
#define CC 64
#define C8K 8
#define NN 9216
#define SPLIT 4
#define MCHUNK 128
#define MRANGE (NN / SPLIT)   // 2304, divisible by MCHUNK
#define TQ 64
#define SHIFT 12.0f

// workspace float offsets (total ~25 MB)
#define OFF_Q 0
#define OFF_K (OFF_Q + BN * NN * C8K)            // 147456
#define OFF_V (OFF_K + BN * NN * C8K)            // 294912
#define OFF_PACC (OFF_V + BN * NN * CC)          // 1474560
#define OFF_PSUM (OFF_PACC + SPLIT * BN * NN * CC) // 6193152
#define WS_FLOATS (OFF_PSUM + SPLIT * BN * NN)   // 6266880 floats = 25.07 MB

__global__ __launch_bounds__(256) void pam_prep(
    const float* __restrict__ fm, const float* __restrict__ depth,
    const float* __restrict__ wa, const float* __restrict__ ba,
    const float* __restrict__ wb, const float* __restrict__ bb,
    const float* __restrict__ wc, const float* __restrict__ bc,
    const float* __restrict__ wd, const float* __restrict__ bd,
    float* __restrict__ Q, float* __restrict__ K, float* __restrict__ V)
{
    __shared__ float s_wb[C8K * CC], s_wc[C8K * CC], s_wd[CC * CC];
    __shared__ float s_wa[CC], s_ba[CC], s_bd[CC], s_bb[C8K], s_bc[C8K];
    int t = threadIdx.x;
    for (int i = t; i < C8K * CC; i += 256) { s_wb[i] = wb[i]; s_wc[i] = wc[i]; }
    for (int i = t; i < CC * CC; i += 256) s_wd[i] = wd[i];
    if (t < CC) { s_wa[t] = wa[t]; s_ba[t] = ba[t]; s_bd[t] = bd[t]; }
    if (t < C8K) { s_bb[t] = bb[t]; s_bc[t] = bc[t]; }
    __syncthreads();

    int idx = blockIdx.x * 256 + t;   // b*N + m, grid exact (72*256 = 18432)
    int b = idx / NN;
    int m = idx - b * NN;

    float d = depth[idx];
    float df[CC];
#pragma unroll
    for (int i = 0; i < CC; ++i) df[i] = fmaxf(s_wa[i] * d + s_ba[i], 0.0f);

    // Q[b,n,k] = sum_i wb[k,i]*fm[b,i,n] + bb[k]
    float q[C8K];
#pragma unroll
    for (int k = 0; k < C8K; ++k) q[k] = s_bb[k];
    for (int i = 0; i < CC; ++i) {
        float f = fm[(b * CC + i) * NN + m];
#pragma unroll
        for (int k = 0; k < C8K; ++k) q[k] += s_wb[k * CC + i] * f;
    }
#pragma unroll
    for (int k = 0; k < C8K; ++k) Q[idx * C8K + k] = q[k];

    // K[b,k,m] = sum_i wc[k,i]*df[i] + bc[k]
    float kk[C8K];
#pragma unroll
    for (int k = 0; k < C8K; ++k) kk[k] = s_bc[k];
    for (int i = 0; i < CC; ++i) {
#pragma unroll
        for (int k = 0; k < C8K; ++k) kk[k] += s_wc[k * CC + i] * df[i];
    }
#pragma unroll
    for (int k = 0; k < C8K; ++k) K[(b * C8K + k) * NN + m] = kk[k];

    // V[b,m,c] = sum_i wd[c,i]*df[i] + bd[c]
    for (int c = 0; c < CC; ++c) {
        float s = s_bd[c];
#pragma unroll
        for (int i = 0; i < CC; ++i) s += s_wd[c * CC + i] * df[i];
        V[idx * CC + c] = s;
    }
}

// grid (N/TQ, SPLIT, B), block 256 (4 waves).
// Block computes, for rows n0..n0+63 and its m-range, the partial
// unnormalized accumulation ACC[r][c] = sum_m e(r,m)*V[m][c] and row sums.
__global__ __launch_bounds__(256) void pam_attn(
    const float* __restrict__ Q, const float* __restrict__ K,
    const float* __restrict__ V,
    float* __restrict__ PACC, float* __restrict__ PSUM)
{
    __shared__ float q_s[TQ * C8K];          // 2 KB
    __shared__ float p_s[TQ * MCHUNK];       // 32 KB, [r][m_l]
    __shared__ float acc_s[TQ * (CC + 1)];   // 16.25 KB, padded
    __shared__ float rsum_s[TQ];

    int t = threadIdx.x;
    int n0 = blockIdx.x * TQ;
    int split = blockIdx.y;
    int b = blockIdx.z;
    int m_start = split * MRANGE;

    for (int i = t; i < TQ * (CC + 1); i += 256) acc_s[i] = 0.0f;
    if (t < TQ) rsum_s[t] = 0.0f;
    for (int i = t; i < TQ * C8K; i += 256) q_s[i] = Q[(b * NN + n0) * C8K + i];

    int lane = t & 63, wave = t >> 6;
    int sm = t & 127, sg = t >> 7;   // staging: m_l = sm, rows sg*32..sg*32+31
    int c = lane;                    // accum: channel = lane, wave owns m-slice

    float rsum_part[32];
#pragma unroll
    for (int j = 0; j < 32; ++j) rsum_part[j] = 0.0f;
    float acc[TQ];
#pragma unroll
    for (int r = 0; r < TQ; ++r) acc[r] = 0.0f;

    for (int ch = 0; ch < MRANGE; ch += MCHUNK) {
        __syncthreads();   // prev accum done (and covers init on first iter)
        // ---- stage p = exp(q·k - SHIFT) for 128 m's x 64 rows ----
        {
            int m = m_start + ch + sm;
            float k8[C8K];
#pragma unroll
            for (int j = 0; j < C8K; ++j) k8[j] = K[(b * C8K + j) * NN + m];
#pragma unroll
            for (int jj = 0; jj < 32; ++jj) {
                int r = sg * 32 + jj;
                const float* qr = &q_s[r * C8K];
                float s = qr[0]*k8[0] + qr[1]*k8[1] + qr[2]*k8[2] + qr[3]*k8[3]
                        + qr[4]*k8[4] + qr[5]*k8[5] + qr[6]*k8[6] + qr[7]*k8[7];
                float e = __expf(s - SHIFT);
                p_s[r * MCHUNK + sm] = e;     // stride-1 in sm: conflict-free
                rsum_part[jj] += e;
            }
        }
        __syncthreads();
        // ---- accumulate acc[r] += p[r][m]*V[m][c] over wave's 32 m's ----
        {
            int mrow = b * NN + m_start + ch + wave * 32;
            for (int ml4 = 0; ml4 < 8; ++ml4) {
                const float* vp = &V[(mrow + ml4 * 4) * CC + c];
                float v0 = vp[0], v1 = vp[CC], v2 = vp[2 * CC], v3 = vp[3 * CC];
                const float4* pp = (const float4*)&p_s[wave * 32 + ml4 * 4];
#pragma unroll
                for (int r = 0; r < TQ; ++r) {
                    float4 p4 = pp[r * (MCHUNK / 4)];  // same addr across wave: broadcast
                    acc[r] += p4.x * v0 + p4.y * v1 + p4.z * v2 + p4.w * v3;
                }
            }
        }
    }

    // rowsum: butterfly within wave, then combine the 2 waves per row-group
#pragma unroll
    for (int jj = 0; jj < 32; ++jj) {
        float v = rsum_part[jj];
        for (int off = 32; off > 0; off >>= 1) v += __shfl_xor(v, off);
        rsum_part[jj] = v;
    }
    if (lane == 0) {
        for (int jj = 0; jj < 32; ++jj)
            atomicAdd(&rsum_s[sg * 32 + jj], rsum_part[jj]);
    }
    // acc: combine 4 waves per (r,c)
#pragma unroll
    for (int r = 0; r < TQ; ++r) atomicAdd(&acc_s[r * (CC + 1) + c], acc[r]);
    __syncthreads();

    int slab = (split * BN + b) * NN;
    for (int i = t; i < TQ * CC; i += 256) {
        int r = i >> 6, cc2 = i & 63;
        PACC[(slab + n0 + r) * CC + cc2] = acc_s[r * (CC + 1) + cc2];
    }
    if (t < TQ) PSUM[slab + n0 + t] = rsum_s[t];
}

// combine splits, normalize, transpose [n][c] -> out[b][c][n]
__global__ __launch_bounds__(256) void pam_norm(
    const float* __restrict__ PACC, const float* __restrict__ PSUM,
    float* __restrict__ out)
{
    __shared__ float tile[TQ * (CC + 1)];
    __shared__ float sums[TQ];
    int t = threadIdx.x;
    int n0 = blockIdx.x * TQ;
    int b = blockIdx.y;
    if (t < TQ) {
        float s = 0.0f;
#pragma unroll
        for (int sp = 0; sp < SPLIT; ++sp) s += PSUM[(sp * BN + b) * NN + n0 + t];
        sums[t] = s;
    }
    __syncthreads();
    int lane = t & 63, wv = t >> 6;
    for (int rr = wv * 16; rr < wv * 16 + 16; ++rr) {
        float a = 0.0f;
#pragma unroll
        for (int sp = 0; sp < SPLIT; ++sp)
            a += PACC[((sp * BN + b) * NN + n0 + rr) * CC + lane];
        tile[rr * (CC + 1) + lane] = a / sums[rr];
    }
    __syncthreads();
    for (int i = t; i < CC * TQ; i += 256) {
        int chn = i >> 6, nn2 = i & 63;
        out[(b * CC + chn) * NN + n0 + nn2] = tile[nn2 * (CC + 1) + chn];
    }
}

extern "C" void kernel_launch(void* const* d_in, const int* in_sizes, int n_in,
                              void* d_out, int out_size, void* d_ws, size_t ws_size,
                              hipStream_t stream) {
    const float* fm    = (const float*)d_in[0];
    const float* depth = (const float*)d_in[1];
    const float* wa    = (const float*)d_in[2];
    const float* ba    = (const float*)d_in[3];
    const float* wb    = (const float*)d_in[4];
    const float* bb    = (const float*)d_in[5];
    const float* wc    = (const float*)d_in[6];
    const float* bc    = (const float*)d_in[7];
    const float* wd    = (const float*)d_in[8];
    const float* bd    = (const float*)d_in[9];
    float* out = (float*)d_out;

    float* ws   = (float*)d_ws;
    float* Q    = ws + OFF_Q;
    float* K    = ws + OFF_K;
    float* V    = ws + OFF_V;
    float* PACC = ws + OFF_PACC;
    float* PSUM = ws + OFF_PSUM;

    pam_prep<<<dim3((BN * NN) / 256), 256, 0, stream>>>(
        fm, depth, wa, ba, wb, bb, wc, bc, wd, bd, Q, K, V);
    pam_attn<<<dim3(NN / TQ, SPLIT, BN), 256, 0, stream>>>(Q, K, V, PACC, PSUM);
    pam_norm<<<dim3(NN / TQ, BN), 256, 0, stream>>>(PACC, PSUM, out);
}

// Round 2
// 247.418 us; speedup vs baseline: 4.3799x; 4.3799x over previous
//
#include <hip/hip_runtime.h>

// PositionAttentionModule: B=2,C=64,C8=8,H=W=96,N=9216
// out[b,c,n] = sum_m V[b,m,c]*softmax_m(Q[b,n,:]·K[b,:,m])
// Round 2: QK+exp staging in fp32 VALU -> bf16 P tile in LDS -> PV via
// v_mfma_f32_16x16x32_bf16 against bf16 V^T tile. Constant-shift softmax.

#define BN 2
#define CC 64
#define C8K 8
#define NN 9216
#define SPLIT 4
#define MCHUNK 128
#define MRANGE (NN / SPLIT)   // 2304 = 18 chunks of 128
#define TQ 64
#define SHIFT 12.0f
#define PSTR (MCHUNK + 8)     // 136 bf16 -> 272 B row stride (16B aligned, 4-bank shift)

typedef __attribute__((ext_vector_type(8))) short short8;
typedef __attribute__((ext_vector_type(4))) float f32x4;

// float offsets into workspace
#define OFF_Q 0
#define OFF_K (OFF_Q + BN * NN * C8K)              // Q: fp32 [b][n][8]
#define OFF_VT (OFF_K + BN * NN * C8K)             // K: fp32 [b][8][m]
#define OFF_PACC (OFF_VT + BN * CC * NN / 2)       // Vt: bf16 [b][c][m] (half float count)
#define OFF_PSUM (OFF_PACC + SPLIT * BN * NN * CC)
#define WS_FLOATS (OFF_PSUM + SPLIT * BN * NN)     // ~22.7 MB

static __device__ inline unsigned short f2bf(float x) {
    unsigned u = __builtin_bit_cast(unsigned, x);
    unsigned r = (u + 0x7fff + ((u >> 16) & 1)) >> 16;   // RNE
    return (unsigned short)r;
}

__global__ __launch_bounds__(256) void pam_prep(
    const float* __restrict__ fm, const float* __restrict__ depth,
    const float* __restrict__ wa, const float* __restrict__ ba,
    const float* __restrict__ wb, const float* __restrict__ bb,
    const float* __restrict__ wc, const float* __restrict__ bc,
    const float* __restrict__ wd, const float* __restrict__ bd,
    float* __restrict__ Q, float* __restrict__ K, unsigned short* __restrict__ Vt)
{
    __shared__ float s_wb[C8K * CC], s_wc[C8K * CC], s_wd[CC * CC];
    __shared__ float s_wa[CC], s_ba[CC], s_bd[CC], s_bb[C8K], s_bc[C8K];
    int t = threadIdx.x;
    for (int i = t; i < C8K * CC; i += 256) { s_wb[i] = wb[i]; s_wc[i] = wc[i]; }
    for (int i = t; i < CC * CC; i += 256) s_wd[i] = wd[i];
    if (t < CC) { s_wa[t] = wa[t]; s_ba[t] = ba[t]; s_bd[t] = bd[t]; }
    if (t < C8K) { s_bb[t] = bb[t]; s_bc[t] = bc[t]; }
    __syncthreads();

    int idx = blockIdx.x * 256 + t;   // b*N + m
    int b = idx / NN;
    int m = idx - b * NN;

    float d = depth[idx];
    float df[CC];
#pragma unroll
    for (int i = 0; i < CC; ++i) df[i] = fmaxf(s_wa[i] * d + s_ba[i], 0.0f);

    float q[C8K];
#pragma unroll
    for (int k = 0; k < C8K; ++k) q[k] = s_bb[k];
    for (int i = 0; i < CC; ++i) {
        float f = fm[(b * CC + i) * NN + m];
#pragma unroll
        for (int k = 0; k < C8K; ++k) q[k] += s_wb[k * CC + i] * f;
    }
#pragma unroll
    for (int k = 0; k < C8K; ++k) Q[idx * C8K + k] = q[k];

    float kk[C8K];
#pragma unroll
    for (int k = 0; k < C8K; ++k) kk[k] = s_bc[k];
    for (int i = 0; i < CC; ++i) {
#pragma unroll
        for (int k = 0; k < C8K; ++k) kk[k] += s_wc[k * CC + i] * df[i];
    }
#pragma unroll
    for (int k = 0; k < C8K; ++k) K[(b * C8K + k) * NN + m] = kk[k];

    // Vt[b][c][m] bf16 (transposed: B^T layout for MFMA B-fragments)
    for (int c = 0; c < CC; ++c) {
        float s = s_bd[c];
#pragma unroll
        for (int i = 0; i < CC; ++i) s += s_wd[c * CC + i] * df[i];
        Vt[(b * CC + c) * NN + m] = f2bf(s);
    }
}

// grid (N/TQ, SPLIT, B), block 256 = 4 waves.
// Wave w owns query rows [w*16, w*16+16) x all 64 channels (4 MFMA tiles).
__global__ __launch_bounds__(256) void pam_attn(
    const float* __restrict__ Q, const float* __restrict__ K,
    const unsigned short* __restrict__ Vt,
    float* __restrict__ PACC, float* __restrict__ PSUM)
{
    __shared__ float q_s[TQ * C8K];              // 2 KB
    __shared__ unsigned short p_s[TQ * PSTR];    // 17 KB bf16 [r][m]
    __shared__ unsigned short v_s[CC * PSTR];    // 17 KB bf16 [c][m]

    int t = threadIdx.x;
    int n0 = blockIdx.x * TQ;
    int split = blockIdx.y;
    int b = blockIdx.z;
    int m_start = split * MRANGE;

    for (int i = t; i < TQ * C8K; i += 256) q_s[i] = Q[(b * NN + n0) * C8K + i];

    int lane = t & 63, w = t >> 6;
    int mp = lane;            // staging: m-pair index within chunk, rows w*16..+15
    int vc = t >> 2, vseg = t & 3;  // V staging: row c, 32-element segment

    f32x4 acc0 = {0,0,0,0}, acc1 = {0,0,0,0}, acc2 = {0,0,0,0}, acc3 = {0,0,0,0};
    float rsum[16];
#pragma unroll
    for (int j = 0; j < 16; ++j) rsum[j] = 0.0f;

    const int row = lane & 15, quad = lane >> 4;
    const unsigned short* pr = &p_s[(w * 16 + row) * PSTR + quad * 8];
    const unsigned short* vr = &v_s[row * PSTR + quad * 8];

    for (int ch = 0; ch < MRANGE; ch += MCHUNK) {
        __syncthreads();   // previous MFMA reads done before overwriting tiles
        int m0 = m_start + ch;
        // ---- stage V chunk: Vt[b][c][m0..m0+127] -> v_s[c][*] ----
        {
            const uint4* src = (const uint4*)&Vt[(b * CC + vc) * NN + m0 + vseg * 32];
            uint4* dst = (uint4*)&v_s[vc * PSTR + vseg * 32];
#pragma unroll
            for (int i = 0; i < 4; ++i) dst[i] = src[i];
        }
        // ---- stage P = exp(q.k - SHIFT) as bf16: 2 m's x 16 rows/thread ----
        {
            int m = m0 + 2 * mp;
            float2 k2[C8K];
#pragma unroll
            for (int j = 0; j < C8K; ++j)
                k2[j] = *(const float2*)&K[(b * C8K + j) * NN + m];
#pragma unroll
            for (int rr = 0; rr < 16; ++rr) {
                const float* qr = &q_s[(w * 16 + rr) * C8K];
                float s0 = 0.0f, s1 = 0.0f;
#pragma unroll
                for (int j = 0; j < C8K; ++j) {
                    s0 += qr[j] * k2[j].x;
                    s1 += qr[j] * k2[j].y;
                }
                float e0 = __expf(s0 - SHIFT), e1 = __expf(s1 - SHIFT);
                rsum[rr] += e0 + e1;
                unsigned pk = (unsigned)f2bf(e0) | ((unsigned)f2bf(e1) << 16);
                *(unsigned*)&p_s[(w * 16 + rr) * PSTR + 2 * mp] = pk;
            }
        }
        __syncthreads();
        // ---- PV via MFMA: 4 k-steps x 4 channel tiles ----
#pragma unroll
        for (int kk = 0; kk < 4; ++kk) {
            short8 a = *(const short8*)(pr + kk * 32);
            short8 b0 = *(const short8*)(vr + 0 * 16 * PSTR + kk * 32);
            short8 b1 = *(const short8*)(vr + 1 * 16 * PSTR + kk * 32);
            short8 b2 = *(const short8*)(vr + 2 * 16 * PSTR + kk * 32);
            short8 b3 = *(const short8*)(vr + 3 * 16 * PSTR + kk * 32);
            acc0 = __builtin_amdgcn_mfma_f32_16x16x32_bf16(a, b0, acc0, 0, 0, 0);
            acc1 = __builtin_amdgcn_mfma_f32_16x16x32_bf16(a, b1, acc1, 0, 0, 0);
            acc2 = __builtin_amdgcn_mfma_f32_16x16x32_bf16(a, b2, acc2, 0, 0, 0);
            acc3 = __builtin_amdgcn_mfma_f32_16x16x32_bf16(a, b3, acc3, 0, 0, 0);
        }
    }

    // ---- epilogue ----
    int slab = (split * BN + b) * NN;
    // rsum: reduce across the 64 lanes of this wave (each lane had 2 m's/chunk)
#pragma unroll
    for (int rr = 0; rr < 16; ++rr) {
        float v = rsum[rr];
#pragma unroll
        for (int off = 32; off > 0; off >>= 1) v += __shfl_xor(v, off);
        rsum[rr] = v;
    }
    if (lane == 0) {
#pragma unroll
        for (int rr = 0; rr < 16; ++rr)
            PSUM[slab + n0 + w * 16 + rr] = rsum[rr];
    }
    // acc tiles: C/D layout col=lane&15, row=(lane>>4)*4+reg
    {
        float* base = &PACC[(slab + n0 + w * 16) * CC];
#pragma unroll
        for (int reg = 0; reg < 4; ++reg) {
            int r = quad * 4 + reg;
            base[r * CC + 0 * 16 + row] = acc0[reg];
            base[r * CC + 1 * 16 + row] = acc1[reg];
            base[r * CC + 2 * 16 + row] = acc2[reg];
            base[r * CC + 3 * 16 + row] = acc3[reg];
        }
    }
}

// combine splits, normalize, transpose [n][c] -> out[b][c][n]
__global__ __launch_bounds__(256) void pam_norm(
    const float* __restrict__ PACC, const float* __restrict__ PSUM,
    float* __restrict__ out)
{
    __shared__ float tile[TQ * (CC + 1)];
    __shared__ float sums[TQ];
    int t = threadIdx.x;
    int n0 = blockIdx.x * TQ;
    int b = blockIdx.y;
    if (t < TQ) {
        float s = 0.0f;
#pragma unroll
        for (int sp = 0; sp < SPLIT; ++sp) s += PSUM[(sp * BN + b) * NN + n0 + t];
        sums[t] = s;
    }
    __syncthreads();
    int lane = t & 63, wv = t >> 6;
    for (int rr = wv * 16; rr < wv * 16 + 16; ++rr) {
        float a = 0.0f;
#pragma unroll
        for (int sp = 0; sp < SPLIT; ++sp)
            a += PACC[((sp * BN + b) * NN + n0 + rr) * CC + lane];
        tile[rr * (CC + 1) + lane] = a / sums[rr];
    }
    __syncthreads();
    for (int i = t; i < CC * TQ; i += 256) {
        int chn = i >> 6, nn2 = i & 63;
        out[(b * CC + chn) * NN + n0 + nn2] = tile[nn2 * (CC + 1) + chn];
    }
}

extern "C" void kernel_launch(void* const* d_in, const int* in_sizes, int n_in,
                              void* d_out, int out_size, void* d_ws, size_t ws_size,
                              hipStream_t stream) {
    const float* fm    = (const float*)d_in[0];
    const float* depth = (const float*)d_in[1];
    const float* wa    = (const float*)d_in[2];
    const float* ba    = (const float*)d_in[3];
    const float* wb    = (const float*)d_in[4];
    const float* bb    = (const float*)d_in[5];
    const float* wc    = (const float*)d_in[6];
    const float* bc    = (const float*)d_in[7];
    const float* wd    = (const float*)d_in[8];
    const float* bd    = (const float*)d_in[9];
    float* out = (float*)d_out;

    float* ws   = (float*)d_ws;
    float* Q    = ws + OFF_Q;
    float* K    = ws + OFF_K;
    unsigned short* Vt = (unsigned short*)(ws + OFF_VT);
    float* PACC = ws + OFF_PACC;
    float* PSUM = ws + OFF_PSUM;

    pam_prep<<<dim3((BN * NN) / 256), 256, 0, stream>>>(
        fm, depth, wa, ba, wb, bb, wc, bc, wd, bd, Q, K, Vt);
    pam_attn<<<dim3(NN / TQ, SPLIT, BN), 256, 0, stream>>>(Q, K, Vt, PACC, PSUM);
    pam_norm<<<dim3(NN / TQ, BN), 256, 0, stream>>>(PACC, PSUM, out);
}

// Round 3
// 172.918 us; speedup vs baseline: 6.2670x; 1.4308x over previous
//
#include <hip/hip_runtime.h>

// PositionAttentionModule: B=2,C=64,C8=8,H=W=96,N=9216
// out[b,c,n] = sum_m V[b,m,c]*softmax_m(Q[b,n,:]·K[b,:,m])
// Round 3: QK^T via MFMA (bf16 Q/K frags, K=8 zero-padded to 32), exp on
// C-layout regs, bf16 P -> LDS (wave-private rows, no extra barrier),
// PV via MFMA. Prep re-parallelized to 288 blocks.

#define BN 2
#define CC 64
#define C8K 8
#define NN 9216
#define SPLIT 4
#define MCHUNK 128
#define MRANGE (NN / SPLIT)   // 2304 = 18 chunks of 128
#define TQ 64
#define NBLK (NN / TQ)        // 144
#define PSTR 136              // bf16 row stride (272 B: 16B-aligned, 4-bank shift)

typedef __attribute__((ext_vector_type(8))) short short8;
typedef __attribute__((ext_vector_type(4))) float f32x4;

// float offsets into workspace (total ~22.1 MB)
#define OFF_QB 0                                   // bf16 [b][n][8]
#define OFF_KT (OFF_QB + BN * NN * C8K / 2)        // bf16 [b][m][8]
#define OFF_VT (OFF_KT + BN * NN * C8K / 2)        // bf16 [b][c][m]
#define OFF_PACC (OFF_VT + BN * NN * CC / 2)
#define OFF_PSUM (OFF_PACC + SPLIT * BN * NN * CC)
#define WS_FLOATS (OFF_PSUM + SPLIT * BN * NN)

static __device__ inline unsigned short f2bf(float x) {
    unsigned u = __builtin_bit_cast(unsigned, x);
    unsigned r = (u + 0x7fff + ((u >> 16) & 1)) >> 16;   // RNE
    return (unsigned short)r;
}

// grid 288 blocks: each block = 64 pixels, 4 waves split the channel work.
__global__ __launch_bounds__(256) void pam_prep(
    const float* __restrict__ fm, const float* __restrict__ depth,
    const float* __restrict__ wa, const float* __restrict__ ba,
    const float* __restrict__ wb, const float* __restrict__ bb,
    const float* __restrict__ wc, const float* __restrict__ bc,
    const float* __restrict__ wd, const float* __restrict__ bd,
    unsigned short* __restrict__ Qb, unsigned short* __restrict__ Kt,
    unsigned short* __restrict__ Vt)
{
    __shared__ float s_wd[CC * CC];                // 16 KB
    __shared__ float s_wb[C8K * CC], s_wc[C8K * CC];
    __shared__ float s_wa[CC], s_ba[CC], s_bd[CC];
    __shared__ float s_bb[C8K], s_bc[C8K];
    __shared__ float qp[4][TQ][C8K + 1];           // 9.2 KB, padded

    int t = threadIdx.x;
    for (int i = t; i < CC * CC; i += 256) s_wd[i] = wd[i];
    for (int i = t; i < C8K * CC; i += 256) { s_wb[i] = wb[i]; s_wc[i] = wc[i]; }
    if (t < CC) { s_wa[t] = wa[t]; s_ba[t] = ba[t]; s_bd[t] = bd[t]; }
    if (t < C8K) { s_bb[t] = bb[t]; s_bc[t] = bc[t]; }
    __syncthreads();

    int px0 = blockIdx.x * TQ;       // flat b*NN + m base (blocks never straddle b)
    int b = px0 / NN;
    int m0 = px0 - b * NN;
    int px = t & 63, w = t >> 6;
    int m = m0 + px;
    int gidx = px0 + px;

    float d = depth[gidx];
    float df[CC];
#pragma unroll
    for (int i = 0; i < CC; ++i) df[i] = fmaxf(s_wa[i] * d + s_ba[i], 0.0f);

    // V: wave w -> channels [w*16, w*16+16), coalesced bf16 stores
#pragma unroll 4
    for (int cc = 0; cc < 16; ++cc) {
        int c = w * 16 + cc;
        float acc = s_bd[c];
#pragma unroll
        for (int i = 0; i < CC; i += 4) {
            float4 wv = *(const float4*)&s_wd[c * CC + i];
            acc += wv.x * df[i] + wv.y * df[i + 1] + wv.z * df[i + 2] + wv.w * df[i + 3];
        }
        Vt[(b * CC + c) * NN + m] = f2bf(acc);
    }

    // K: wave w -> k channels {2w, 2w+1}; pack pair into one dword store
    {
        float k0 = s_bc[2 * w], k1 = s_bc[2 * w + 1];
#pragma unroll
        for (int i = 0; i < CC; ++i) {
            k0 += s_wc[(2 * w) * CC + i] * df[i];
            k1 += s_wc[(2 * w + 1) * CC + i] * df[i];
        }
        unsigned pk = (unsigned)f2bf(k0) | ((unsigned)f2bf(k1) << 16);
        *(unsigned*)&Kt[(b * NN + m) * C8K + 2 * w] = pk;
    }

    // Q partials: wave w sums i in [w*16, w*16+16)
    {
        float q[C8K];
#pragma unroll
        for (int k = 0; k < C8K; ++k) q[k] = (w == 0) ? s_bb[k] : 0.0f;
#pragma unroll
        for (int ii = 0; ii < 16; ++ii) {
            int i = w * 16 + ii;
            float f = fm[(b * CC + i) * NN + m];
#pragma unroll
            for (int k = 0; k < C8K; ++k) q[k] += s_wb[k * CC + i] * f;
        }
#pragma unroll
        for (int k = 0; k < C8K; ++k) qp[w][px][k] = q[k];
    }
    __syncthreads();
    // reduce 4 partials, pack bf16 pairs, coalesced dword stores
    {
        int px2 = t >> 2, k2 = (t & 3) * 2;
        float a0 = qp[0][px2][k2] + qp[1][px2][k2] + qp[2][px2][k2] + qp[3][px2][k2];
        float a1 = qp[0][px2][k2 + 1] + qp[1][px2][k2 + 1] + qp[2][px2][k2 + 1] + qp[3][px2][k2 + 1];
        unsigned pk = (unsigned)f2bf(a0) | ((unsigned)f2bf(a1) << 16);
        *(unsigned*)&Qb[(px0 + px2) * C8K + k2] = pk;
    }
}

// grid (144, SPLIT, B), block 256 = 4 waves. Wave w owns query rows
// [w*16, w*16+16) x all 64 channels. QK and PV both on MFMA.
__global__ __launch_bounds__(256, 4) void pam_attn(
    const unsigned short* __restrict__ Qb, const unsigned short* __restrict__ Kt,
    const unsigned short* __restrict__ Vt,
    float* __restrict__ PACC, float* __restrict__ PSUM)
{
    __shared__ unsigned short p_s[TQ * PSTR];     // 17 KB bf16 [r][m]
    __shared__ unsigned short v_s[CC * PSTR];     // 17 KB bf16 [c][m]
    __shared__ unsigned short k_s[MCHUNK * C8K];  // 2 KB bf16 [m][k]

    int t = threadIdx.x;
    int n0 = blockIdx.x * TQ;
    int split = blockIdx.y;
    int b = blockIdx.z;
    int m_start = split * MRANGE;

    int lane = t & 63, w = t >> 6;
    int col16 = lane & 15, quad = lane >> 4;
    int vc = t >> 2, vseg = t & 3;   // V staging: channel, 32-elem segment

    const f32x4 z4 = {0.0f, 0.0f, 0.0f, 0.0f};

    // loop-invariant A-frag for QK: Q rows, k=0..8 real (quad 0), rest zero
    short8 aq = {0, 0, 0, 0, 0, 0, 0, 0};
    if (quad == 0)
        aq = *(const short8*)&Qb[(b * NN + n0 + w * 16 + col16) * C8K];

    f32x4 acc0 = z4, acc1 = z4, acc2 = z4, acc3 = z4;
    float rsum[4] = {0.0f, 0.0f, 0.0f, 0.0f};

    const unsigned short* pA = &p_s[(w * 16 + col16) * PSTR + quad * 8];
    const unsigned short* pB = &v_s[col16 * PSTR + quad * 8];

    for (int ch = 0; ch < MRANGE; ch += MCHUNK) {
        int m0 = m_start + ch;
        __syncthreads();   // prior chunk's v_s/k_s reads complete
        // ---- stage V chunk [c][128m] ----
        {
            const uint4* src = (const uint4*)&Vt[(b * CC + vc) * NN + m0 + vseg * 32];
            uint4* dst = (uint4*)&v_s[vc * PSTR + vseg * 32];
#pragma unroll
            for (int i = 0; i < 4; ++i) dst[i] = src[i];
        }
        // ---- stage K chunk [128m][8k] ----
        if (t < MCHUNK)
            *(uint4*)&k_s[t * C8K] = *(const uint4*)&Kt[(b * NN + m0 + t) * C8K];
        __syncthreads();

        // ---- QK^T: 8 m-tiles via MFMA ----
        f32x4 sacc[8];
#pragma unroll
        for (int mt = 0; mt < 8; ++mt) {
            short8 bk = *(const short8*)&k_s[(mt * 16 + col16) * C8K];
            sacc[mt] = __builtin_amdgcn_mfma_f32_16x16x32_bf16(aq, bk, z4, 0, 0, 0);
        }
        // ---- exp + rowsum + pack P (wave-private rows: no barrier needed) ----
#pragma unroll
        for (int mt = 0; mt < 8; ++mt) {
#pragma unroll
            for (int r = 0; r < 4; ++r) {
                float e = __expf(sacc[mt][r]);
                rsum[r] += e;
                p_s[(w * 16 + quad * 4 + r) * PSTR + mt * 16 + col16] = f2bf(e);
            }
        }
        // ---- PV via MFMA: 4 k-steps x 4 channel tiles ----
#pragma unroll
        for (int kk = 0; kk < 4; ++kk) {
            short8 a = *(const short8*)(pA + kk * 32);
            short8 b0 = *(const short8*)(pB + 0 * 16 * PSTR + kk * 32);
            short8 b1 = *(const short8*)(pB + 1 * 16 * PSTR + kk * 32);
            short8 b2 = *(const short8*)(pB + 2 * 16 * PSTR + kk * 32);
            short8 b3 = *(const short8*)(pB + 3 * 16 * PSTR + kk * 32);
            acc0 = __builtin_amdgcn_mfma_f32_16x16x32_bf16(a, b0, acc0, 0, 0, 0);
            acc1 = __builtin_amdgcn_mfma_f32_16x16x32_bf16(a, b1, acc1, 0, 0, 0);
            acc2 = __builtin_amdgcn_mfma_f32_16x16x32_bf16(a, b2, acc2, 0, 0, 0);
            acc3 = __builtin_amdgcn_mfma_f32_16x16x32_bf16(a, b3, acc3, 0, 0, 0);
        }
    }

    // ---- epilogue ----
    int slab = (split * BN + b) * NN;
    // row sums: rows w*16+quad*4+r live across the 16 lanes of each quad
#pragma unroll
    for (int r = 0; r < 4; ++r) {
        float v = rsum[r];
        v += __shfl_xor(v, 1); v += __shfl_xor(v, 2);
        v += __shfl_xor(v, 4); v += __shfl_xor(v, 8);
        rsum[r] = v;
    }
    if (col16 == 0) {
#pragma unroll
        for (int r = 0; r < 4; ++r)
            PSUM[slab + n0 + w * 16 + quad * 4 + r] = rsum[r];
    }
    // acc tiles: C/D layout col=lane&15 (channel), row=quad*4+reg (query row)
    {
        float* base = &PACC[(slab + n0 + w * 16) * CC];
#pragma unroll
        for (int reg = 0; reg < 4; ++reg) {
            int r = quad * 4 + reg;
            base[r * CC + 0 * 16 + col16] = acc0[reg];
            base[r * CC + 1 * 16 + col16] = acc1[reg];
            base[r * CC + 2 * 16 + col16] = acc2[reg];
            base[r * CC + 3 * 16 + col16] = acc3[reg];
        }
    }
}

// combine splits, normalize, transpose [n][c] -> out[b][c][n]
__global__ __launch_bounds__(256) void pam_norm(
    const float* __restrict__ PACC, const float* __restrict__ PSUM,
    float* __restrict__ out)
{
    __shared__ float tile[TQ * (CC + 1)];
    __shared__ float sums[TQ];
    int t = threadIdx.x;
    int n0 = blockIdx.x * TQ;
    int b = blockIdx.y;
    if (t < TQ) {
        float s = 0.0f;
#pragma unroll
        for (int sp = 0; sp < SPLIT; ++sp) s += PSUM[(sp * BN + b) * NN + n0 + t];
        sums[t] = s;
    }
    __syncthreads();
    int lane = t & 63, wv = t >> 6;
    for (int rr = wv * 16; rr < wv * 16 + 16; ++rr) {
        float a = 0.0f;
#pragma unroll
        for (int sp = 0; sp < SPLIT; ++sp)
            a += PACC[((sp * BN + b) * NN + n0 + rr) * CC + lane];
        tile[rr * (CC + 1) + lane] = a / sums[rr];
    }
    __syncthreads();
    for (int i = t; i < CC * TQ; i += 256) {
        int chn = i >> 6, nn2 = i & 63;
        out[(b * CC + chn) * NN + n0 + nn2] = tile[nn2 * (CC + 1) + chn];
    }
}

extern "C" void kernel_launch(void* const* d_in, const int* in_sizes, int n_in,
                              void* d_out, int out_size, void* d_ws, size_t ws_size,
                              hipStream_t stream) {
    const float* fm    = (const float*)d_in[0];
    const float* depth = (const float*)d_in[1];
    const float* wa    = (const float*)d_in[2];
    const float* ba    = (const float*)d_in[3];
    const float* wb    = (const float*)d_in[4];
    const float* bb    = (const float*)d_in[5];
    const float* wc    = (const float*)d_in[6];
    const float* bc    = (const float*)d_in[7];
    const float* wd    = (const float*)d_in[8];
    const float* bd    = (const float*)d_in[9];
    float* out = (float*)d_out;

    float* ws = (float*)d_ws;
    unsigned short* Qb = (unsigned short*)(ws + OFF_QB);
    unsigned short* Kt = (unsigned short*)(ws + OFF_KT);
    unsigned short* Vt = (unsigned short*)(ws + OFF_VT);
    float* PACC = ws + OFF_PACC;
    float* PSUM = ws + OFF_PSUM;

    pam_prep<<<dim3((BN * NN) / TQ), 256, 0, stream>>>(
        fm, depth, wa, ba, wb, bb, wc, bc, wd, bd, Qb, Kt, Vt);
    pam_attn<<<dim3(NBLK, SPLIT, BN), 256, 0, stream>>>(Qb, Kt, Vt, PACC, PSUM);
    pam_norm<<<dim3(NBLK, BN), 256, 0, stream>>>(PACC, PSUM, out);
}